// Round 11
// baseline (33.094 us; speedup 1.0000x reference)
//
#include <hip/hip_runtime.h>

// Problem constants (fixed by setup_inputs):
// root_positions:          [B=16, T_IN=64, 3]        f32
// joint_rotations_ortho6d: [B=16, T_IN=64, N=52, 6]  f32
// input_frame_indices:     [64] int (sorted, idx[0]=0)
// target_frame_indices:    [4096] arange (implied, unused)
// Outputs (concat): jp [B, 4160, N, 3] then jr [B, 4160, N, 6], f32
constexpr int B     = 16;
constexpr int T_IN  = 64;
constexpr int NJ    = 52;
constexpr int T_OUT = 4096;
constexpr int T_PAD = T_OUT + T_IN;       // 4160

constexpr int JP_ROW4 = NJ * 3 / 4;       // 39 float4 per jp row
constexpr int JR_ROW4 = NJ * 6 / 4;       // 78 float4 per jr row
constexpr int NROWS   = B * T_PAD;        // 66,560
constexpr size_t NP4  = (size_t)NROWS * JP_ROW4;  // jp section size in float4

constexpr int CHUNK  = 13;                // s_out values per block
constexpr int NCHUNK = T_PAD / CHUNK;     // 320 (exact)
// grid = 320 x 16 = 5120 blocks = EXACTLY 20 blocks/CU (fine-grained, balanced;
// R9's 2080 blocks = 8.125/CU left a ~3µs lone-block tail on 32 CUs).

typedef float f4 __attribute__((ext_vector_type(4)));

__global__ __launch_bounds__(256) void zv_run13(
    const float* __restrict__ root,   // [B, T_IN, 3]
    const float* __restrict__ rot,    // [B, T_IN, NJ, 6]
    const int*   __restrict__ idx,    // [T_IN] sorted, idx[0]=0
    f4*          __restrict__ out4)
{
    __shared__ int   sidx[T_IN];
    __shared__ int   ssel[CHUNK];     // lo | (k<<8)
    __shared__ float sinv[CHUNK];     // 1/k (exactly 1.0f when k==1)
    __shared__ f4    srm[CHUNK];      // per-s root mean (x,y,z,-)

    const int tid = threadIdx.x;
    const int cs  = blockIdx.x * CHUNK;   // chunk start s_out
    const int b   = blockIdx.y;

    if (tid < T_IN) sidx[tid] = idx[tid];
    __syncthreads();

    if (tid < CHUNK) {
        const int s_out = cs + tid;
        int s = s_out - (T_IN - 1);                   // undo front pad
        s = s < 0 ? 0 : (s > T_OUT - 1 ? T_OUT - 1 : s);
        // ub = count of idx[t] <= s in [1,64]; first step 64 (guarded) so
        // ub==64 is reachable for s >= idx[63] (round-4 lesson).
        int ub = 0;
        #pragma unroll
        for (int st = 64; st > 0; st >>= 1)
            if (ub + st <= T_IN && sidx[ub + st - 1] <= s) ub += st;
        const int m = sidx[ub - 1];
        int lo = 0;
        #pragma unroll
        for (int st = 32; st > 0; st >>= 1)
            if (sidx[lo + st - 1] < m) lo += st;
        const int   k   = ub - lo;
        const float inv = 1.0f / (float)k;
        ssel[tid] = lo | (k << 8);
        sinv[tid] = inv;
        const float* rp = root + (size_t)(b * T_IN + lo) * 3;
        float r0 = rp[0], r1 = rp[1], r2 = rp[2];
        for (int q = 1; q < k; ++q) { r0 += rp[3*q]; r1 += rp[3*q+1]; r2 += rp[3*q+2]; }
        f4 v; v.x = r0 * inv; v.y = r1 * inv; v.z = r2 * inv; v.w = 0.f;
        srm[tid] = v;
    }
    __syncthreads();

    // ---- jp: 13 rows x 39 f4 = 507 f4, one contiguous ~8KB span.
    // Non-temporal: don't let the 124.6MB output stream evict rot from L2.
    {
        f4* dst = out4 + (size_t)(b * T_PAD + cs) * JP_ROW4;
        for (int u = tid; u < CHUNK * JP_ROW4; u += 256) {
            const int r  = u / JP_ROW4;               // row within chunk
            const int md = u % 3;                     // 39%3==0 -> elem%3 == u%3
            const f4  rm = srm[r];
            f4 v;
            v.x = md == 0 ? rm.x : (md == 1 ? rm.y : rm.z);
            v.y = md == 0 ? rm.y : (md == 1 ? rm.z : rm.x);
            v.z = md == 0 ? rm.z : (md == 1 ? rm.x : rm.y);
            v.w = v.x;
            __builtin_nontemporal_store(v, &dst[u]);
        }
    }

    // ---- jr: 13 rows x 78 f4; value held in REGISTERS across rows,
    // reloaded only when the selection changes (rare). thread = e + 78*j.
    if (tid < 234) {
        const int e = tid % 78;
        const int j = tid / 78;
        const f4* rotb = (const f4*)rot + ((size_t)b * T_IN * JR_ROW4 + e);
        f4*       dst  = out4 + (NP4 + (size_t)(b * T_PAD + cs) * JR_ROW4 + e);
        int cur = -1;
        f4  a;
        for (int r = j; r < CHUNK; r += 3) {
            const int selr = ssel[r];
            if (selr != cur) {                        // keyframe changed: reload
                cur = selr;
                const int lo = cur & 0xff;
                const int k  = cur >> 8;
                const f4* src = rotb + (size_t)lo * JR_ROW4;
                a = src[0];
                for (int q = 1; q < k; ++q) a += src[(size_t)q * JR_ROW4];
                a *= sinv[r];                         // exact 1.0f when k==1
            }
            __builtin_nontemporal_store(a, &dst[(size_t)r * JR_ROW4]);
        }
    }
}

extern "C" void kernel_launch(void* const* d_in, const int* in_sizes, int n_in,
                              void* d_out, int out_size, void* d_ws, size_t ws_size,
                              hipStream_t stream) {
    const float* root = (const float*)d_in[0];
    const float* rot  = (const float*)d_in[1];
    const int*   idx  = (const int*)d_in[2];
    // d_in[3] = target_frame_indices (arange) — implied by the mapping, unused.
    f4* out4 = (f4*)d_out;

    hipLaunchKernelGGL(zv_run13, dim3(NCHUNK, B), dim3(256), 0, stream,
                       root, rot, idx, out4);
}

// Round 12
// 26.391 us; speedup vs baseline: 1.2540x; 1.2540x over previous
//
#include <hip/hip_runtime.h>

// Problem constants (fixed by setup_inputs):
// root_positions:          [B=16, T_IN=64, 3]        f32
// joint_rotations_ortho6d: [B=16, T_IN=64, N=52, 6]  f32
// input_frame_indices:     [64] int (sorted, idx[0]=0)
// target_frame_indices:    [4096] arange (implied, unused)
// Outputs (concat): jp [B, 4160, N, 3] then jr [B, 4160, N, 6], f32
constexpr int B     = 16;
constexpr int T_IN  = 64;
constexpr int NJ    = 52;
constexpr int T_OUT = 4096;
constexpr int T_PAD = T_OUT + T_IN;       // 4160

constexpr int JP_ROW4 = NJ * 3 / 4;       // 39 float4 per jp row
constexpr int JR_ROW4 = NJ * 6 / 4;       // 78 float4 per jr row
constexpr int NROWS   = B * T_PAD;        // 66,560
constexpr size_t NP4  = (size_t)NROWS * JP_ROW4;  // jp section size in float4

constexpr int CHUNK  = 130;               // s_out values per block (4160 = 32*130)
constexpr int NCHUNK = T_PAD / CHUNK;     // 32
// grid = 32 x 16 = 512 blocks x 1024 threads (16 waves) = EXACTLY 2 blocks/CU
// = 32 waves/CU: whole grid resident in ONE round, zero drain tail (R9's
// 2080x4-wave grid = 8.125 blocks/CU left a ragged second round), and per-block
// setup is paid 512x instead of 2080x.

typedef float f4 __attribute__((ext_vector_type(4)));

__global__ __launch_bounds__(1024) void zv_run130(
    const float* __restrict__ root,   // [B, T_IN, 3]
    const float* __restrict__ rot,    // [B, T_IN, NJ, 6]
    const int*   __restrict__ idx,    // [T_IN] sorted, idx[0]=0
    f4*          __restrict__ out4)
{
    __shared__ int   sidx[T_IN];
    __shared__ int   ssel[CHUNK];     // lo | (k<<8)
    __shared__ float sinv[CHUNK];     // 1/k (exactly 1.0f when k==1)
    __shared__ f4    srm[CHUNK];      // per-s root mean (x,y,z,-)

    const int tid = threadIdx.x;
    const int cs  = blockIdx.x * CHUNK;   // chunk start s_out
    const int b   = blockIdx.y;

    if (tid < T_IN) sidx[tid] = idx[tid];
    __syncthreads();

    if (tid < CHUNK) {
        const int s_out = cs + tid;
        int s = s_out - (T_IN - 1);                   // undo front pad
        s = s < 0 ? 0 : (s > T_OUT - 1 ? T_OUT - 1 : s);
        // ub = count of idx[t] <= s in [1,64]; first step 64 (guarded) so
        // ub==64 is reachable for s >= idx[63] (round-4 lesson).
        int ub = 0;
        #pragma unroll
        for (int st = 64; st > 0; st >>= 1)
            if (ub + st <= T_IN && sidx[ub + st - 1] <= s) ub += st;
        const int m = sidx[ub - 1];
        int lo = 0;
        #pragma unroll
        for (int st = 32; st > 0; st >>= 1)
            if (sidx[lo + st - 1] < m) lo += st;
        const int   k   = ub - lo;
        const float inv = 1.0f / (float)k;
        ssel[tid] = lo | (k << 8);
        sinv[tid] = inv;
        const float* rp = root + (size_t)(b * T_IN + lo) * 3;
        float r0 = rp[0], r1 = rp[1], r2 = rp[2];
        for (int q = 1; q < k; ++q) { r0 += rp[3*q]; r1 += rp[3*q+1]; r2 += rp[3*q+2]; }
        f4 v; v.x = r0 * inv; v.y = r1 * inv; v.z = r2 * inv; v.w = 0.f;
        srm[tid] = v;
    }
    __syncthreads();

    // ---- jp: 130 rows x 39 f4 = 5070 f4, one contiguous ~81KB span ----
    {
        f4* dst = out4 + (size_t)(b * T_PAD + cs) * JP_ROW4;
        for (int u = tid; u < CHUNK * JP_ROW4; u += 1024) {
            const int r  = u / JP_ROW4;               // row within chunk
            const int md = u % 3;                     // 39%3==0 -> elem%3 == u%3
            const f4  rm = srm[r];
            f4 v;
            v.x = md == 0 ? rm.x : (md == 1 ? rm.y : rm.z);
            v.y = md == 0 ? rm.y : (md == 1 ? rm.z : rm.x);
            v.z = md == 0 ? rm.z : (md == 1 ? rm.x : rm.y);
            v.w = v.x;
            dst[u] = v;
        }
    }

    // ---- jr: 130 rows x 78 f4; value held in REGISTERS across rows,
    // reloaded only when selection changes (~2x per 10 rows handled).
    // thread = e + 78*j (e: element, j: row phase 0..12), 1014 lanes active.
    if (tid < 13 * 78) {
        const int e = tid % 78;
        const int j = tid / 78;
        const f4* rotb = (const f4*)rot + ((size_t)b * T_IN * JR_ROW4 + e);
        f4*       dst  = out4 + (NP4 + (size_t)(b * T_PAD + cs) * JR_ROW4 + e);
        int cur = -1;
        f4  a;
        for (int r = j; r < CHUNK; r += 13) {
            const int selr = ssel[r];
            if (selr != cur) {                        // keyframe changed: reload
                cur = selr;
                const int lo = cur & 0xff;
                const int k  = cur >> 8;
                const f4* src = rotb + (size_t)lo * JR_ROW4;
                a = src[0];
                for (int q = 1; q < k; ++q) a += src[(size_t)q * JR_ROW4];
                a *= sinv[r];                         // exact 1.0f when k==1
            }
            dst[(size_t)r * JR_ROW4] = a;             // register-sourced store
        }
    }
}

extern "C" void kernel_launch(void* const* d_in, const int* in_sizes, int n_in,
                              void* d_out, int out_size, void* d_ws, size_t ws_size,
                              hipStream_t stream) {
    const float* root = (const float*)d_in[0];
    const float* rot  = (const float*)d_in[1];
    const int*   idx  = (const int*)d_in[2];
    // d_in[3] = target_frame_indices (arange) — implied by the mapping, unused.
    f4* out4 = (f4*)d_out;

    hipLaunchKernelGGL(zv_run130, dim3(NCHUNK, B), dim3(1024), 0, stream,
                       root, rot, idx, out4);
}